// Round 5
// baseline (4182.424 us; speedup 1.0000x reference)
//
#include <hip/hip_runtime.h>
#include <math.h>

#define B_   64
#define S_   3072
#define DIN  128
#define E_   64
#define H_   256
#define OUT_ 10
#define T_   1024
#define NG   32      // batch groups (2 batches each)
#define GB   2
#define NCH  8       // chunk-WGs per group; WG q owns h-indices [32q,32q+32)
#define GLINES 256   // stamped h lines per group per parity (one per h-index)

// workspace layout (bytes)
#define ACT_BYTES   (B_*E_*T_*4)              // actT[b][e][t] fp32 = 16 MB
#define HBUF_OFF    ACT_BYTES
#define HBUF_BYTES  (NG*2*GLINES*16)          // 256 KB of 16B lines

typedef float f32x4 __attribute__((ext_vector_type(4)));

// IF-coherent access (cross-XCD safe, fence-free). Proven rounds 2/4.
__device__ __forceinline__ f32x4 coh_load_f32x4(const float* p) {
  f32x4 r;
  asm volatile("global_load_dwordx4 %0, %1, off sc0 sc1\n\ts_waitcnt vmcnt(0)"
               : "=v"(r) : "v"(p) : "memory");
  return r;
}
__device__ __forceinline__ void coh_store_f32x4(float* p, f32x4 v) {
  asm volatile("global_store_dwordx4 %0, %1, off sc0 sc1" :: "v"(p), "v"(v) : "memory");
}

__device__ __forceinline__ float fast_sigmoid(float x) {
  return __builtin_amdgcn_rcpf(1.0f + __expf(-x));
}
__device__ __forceinline__ float fast_tanh(float x) {
  return 2.0f * __builtin_amdgcn_rcpf(1.0f + __expf(-2.0f * x)) - 1.0f;
}

// ---------------------------------------------------------------------------
// Conv: normalize rows (L2 over D=128), conv1d k=3 stride=3, +bias, relu.
// ---------------------------------------------------------------------------
__global__ __launch_bounds__(512, 1) void conv_kernel(
    const float* __restrict__ in,     // [B][S][DIN]
    const float* __restrict__ cw,     // [E][DIN][3]
    const float* __restrict__ cb,     // [E]
    float* __restrict__ actT)         // [B][E][T]
{
  extern __shared__ float xs[];                 // 192 rows x 128 f, swizzled
  float4* xs4 = (float4*)xs;
  const int bid = blockIdx.x;
  const int b  = bid >> 4;
  const int tb = bid & 15;
  const int tid = threadIdx.x;

  const float4* gin = (const float4*)(in + (size_t)b*S_*DIN + (size_t)tb*192*DIN);
  #pragma unroll
  for (int i = 0; i < 12; ++i) {
    int f4 = tid + i*512;
    int r = f4 >> 5, dq = f4 & 31;
    xs4[r*32 + (dq ^ (r & 7))] = gin[f4];
  }
  __syncthreads();

  const int wv = tid >> 6, ln = tid & 63;
  for (int rr = 0; rr < 24; ++rr) {
    int r = wv*24 + rr;
    int u = r*32 + ((ln >> 1) ^ (r & 7));
    float2* p = (float2*)((char*)xs + (size_t)u*16 + (size_t)(ln & 1)*8);
    float2 v = *p;
    float s = v.x*v.x + v.y*v.y;
    #pragma unroll
    for (int off = 32; off >= 1; off >>= 1) s += __shfl_xor(s, off);
    float inv = 1.0f / fmaxf(sqrtf(s), 1e-12f);
    v.x *= inv; v.y *= inv;
    *p = v;
  }
  __syncthreads();

  const int eo = __builtin_amdgcn_readfirstlane(wv);
  float acc[8];
  #pragma unroll
  for (int j = 0; j < 8; ++j) acc[j] = cb[eo*8 + j];

  const int r0 = 3*ln, r1 = 3*ln + 1, r2 = 3*ln + 2;
  #pragma unroll 4
  for (int dq = 0; dq < 32; ++dq) {
    float4 x0 = xs4[r0*32 + (dq ^ (r0 & 7))];
    float4 x1 = xs4[r1*32 + (dq ^ (r1 & 7))];
    float4 x2 = xs4[r2*32 + (dq ^ (r2 & 7))];
    #pragma unroll
    for (int j = 0; j < 8; ++j) {
      const float* wp = cw + (size_t)(eo*8 + j)*(DIN*3) + dq*12;  // uniform
      acc[j] += x0.x*wp[0] + x1.x*wp[1] + x2.x*wp[2]
              + x0.y*wp[3] + x1.y*wp[4] + x2.y*wp[5]
              + x0.z*wp[6] + x1.z*wp[7] + x2.z*wp[8]
              + x0.w*wp[9] + x1.w*wp[10] + x2.w*wp[11];
    }
  }

  const int tg = tb*64 + ln;
  #pragma unroll
  for (int j = 0; j < 8; ++j) {
    int e = eo*8 + j;
    actT[(size_t)b*E_*T_ + (size_t)e*T_ + tg] = fmaxf(acc[j], 0.0f);
  }
}

// ---------------------------------------------------------------------------
// LSTM: 256 WGs = 32 groups x 8 chunks; group g = bid&31 (batches 2g,2g+1),
// chunk q = bid>>5 (h-indices [32q,32q+32)).
// Lane = one full gate row (full k = 256 h + 64 x), W row in VGPRs -> no
// cross-thread reduce. Quad lanes (i,f,g,o of one cell) exchange via shfl_xor.
// One barrier per step. h exchange: stamped 16B lines {h_b0, h_b1, _, t}
// (one per h-index), each thread polls exactly one line.
// ---------------------------------------------------------------------------
__global__ __launch_bounds__(256, 1) void lstm_kernel(
    const float* __restrict__ actT,   // [B][E][T]
    const float* __restrict__ w_ih,   // [1024][64]
    const float* __restrict__ w_hh,   // [1024][256]
    const float* __restrict__ b_ih,
    const float* __restrict__ b_hh,
    float* hbuf)                      // [NG][2][GLINES] f32x4 lines
{
  __shared__ float sl[2][2][320];     // [parity][batch][k]: k<256 h, 256+ x

  const int bid = blockIdx.x;
  const int g = bid & 31;
  const int q = bid >> 5;
  const int tid = threadIdx.x;
  const int w = tid >> 6;
  const int l = tid & 63;

  // lane roles: cell (b, hh) x gate m; row = gate row in [0,1024)
  const int hh = 8*w + (l >> 3);            // 0..31 within chunk
  const int b  = (l >> 2) & 1;
  const int m  = l & 3;
  const int row = m*256 + 32*q + hh;

  const int hidx = tid;                     // polled line (0..255)

  // x loader role (tid < 128)
  const int xb = (tid >> 6) & 1, xe = tid & 63;

  // weights -> VGPRs: full row, k-packed [h(64 f4) | x(16 f4)]
  float4 wv[80];
  {
    const float4* ph = (const float4*)(w_hh + (size_t)row*H_);
    #pragma unroll
    for (int i = 0; i < 64; ++i) wv[i] = ph[i];
    const float4* px = (const float4*)(w_ih + (size_t)row*E_);
    #pragma unroll
    for (int i = 0; i < 16; ++i) wv[64+i] = px[i];
  }
  const float bias = b_ih[row] + b_hh[row];

  // init LDS h regions to zero (x regions written every step before use)
  sl[0][0][tid] = 0.f; sl[0][1][tid] = 0.f;
  sl[1][0][tid] = 0.f; sl[1][1][tid] = 0.f;

  float* hb = hbuf + (size_t)g * (2*GLINES*4);            // floats
  const float* actp = actT + (size_t)((g*GB + xb)*E_ + xe) * T_;

  float c = 0.0f;
  for (int t = 0; t < T_; ++t) {
    const int p = t & 1;
    // x prefetch (independent of poll; in flight during it)
    float xval = 0.f;
    if (tid < 128) xval = actp[t];

    // poll my line; line is frozen at stamp t until this WG passes barrier
    if (t > 0) {
      const float* lp = hb + (size_t)(p*GLINES + hidx)*4;
      f32x4 v = coh_load_f32x4(lp);
      while (!__all(__float_as_int(v[3]) == t)) v = coh_load_f32x4(lp);
      sl[p][0][hidx] = v[0];
      sl[p][1][hidx] = v[1];
    }
    if (tid < 128) sl[p][xb][256 + xe] = xval;
    __syncthreads();

    // full-k gate GEMV (LDS reads are 2-way-broadcast, conflict-free)
    float acc = bias;
    {
      const float* hs = &sl[p][b][0];
      #pragma unroll
      for (int i = 0; i < 80; ++i) {
        float4 hv = *(const float4*)(hs + i*4);
        acc += wv[i].x*hv.x + wv[i].y*hv.y + wv[i].z*hv.z + wv[i].w*hv.w;
      }
    }

    // quad exchange: gather all 4 gates of this cell into every quad lane
    float x1 = __shfl_xor(acc, 1);    // gate m^1
    float x2 = __shfl_xor(acc, 2);    // gate m^2
    float x3 = __shfl_xor(x1, 2);     // gate m^3
    float gi = (m==0)?acc:(m==1)?x1:(m==2)?x2:x3;
    float gf = (m==0)?x1 :(m==1)?acc:(m==2)?x3:x2;
    float gg = (m==0)?x2 :(m==1)?x3 :(m==2)?acc:x1;
    float go = (m==0)?x3 :(m==1)?x2 :(m==2)?x1 :acc;

    float si = fast_sigmoid(gi);
    float sf = fast_sigmoid(gf);
    float so = fast_sigmoid(go);
    c = sf*c + si*fast_tanh(gg);
    float h = so*fast_tanh(c);

    // store this chunk's lines: lane (b==0,m==0) of each octet stores one line
    float h1 = __shfl(h, (l & 56) + 4, 64);   // partner (b=1,m=0)
    if ((l & 7) == 0) {
      f32x4 line;
      line[0] = h; line[1] = h1; line[2] = 0.f;
      line[3] = __int_as_float(t + 1);
      float* dp = hb + (size_t)((((t+1) & 1)*GLINES) + 32*q + hh)*4;
      coh_store_f32x4(dp, line);
    }
  }
}

// ---------------------------------------------------------------------------
// Head: out[b][o] = h_last[b] . lin_w[o] + lin_b[o]
// h_last read from hbuf parity 0 lines (stamp T_ = 1024, parity 0).
// Visible cross-kernel: sc1 stores reached memory-side; L1/L2 invalidated at
// kernel boundary.
// ---------------------------------------------------------------------------
__global__ void head_kernel(const float* __restrict__ hbuf,
                            const float* __restrict__ lw,
                            const float* __restrict__ lb,
                            float* __restrict__ out)
{
  int idx = blockIdx.x*blockDim.x + threadIdx.x;
  if (idx >= B_*OUT_) return;
  int b = idx / OUT_, o = idx % OUT_;
  int g = b >> 1, bl = b & 1;
  const float* lines = hbuf + (size_t)g*(2*GLINES*4);   // parity 0 first
  const float* wv = lw + (size_t)o*H_;
  float s = lb[o];
  #pragma unroll 8
  for (int k = 0; k < H_; ++k) s += lines[(size_t)k*4 + bl] * wv[k];
  out[idx] = s;
}

extern "C" void kernel_launch(void* const* d_in, const int* in_sizes, int n_in,
                              void* d_out, int out_size, void* d_ws, size_t ws_size,
                              hipStream_t stream) {
  const float* inputs = (const float*)d_in[0];
  const float* conv_w = (const float*)d_in[3];
  const float* conv_b = (const float*)d_in[4];
  const float* w_ih   = (const float*)d_in[5];
  const float* w_hh   = (const float*)d_in[6];
  const float* b_ih   = (const float*)d_in[7];
  const float* b_hh   = (const float*)d_in[8];
  const float* lin_w  = (const float*)d_in[9];
  const float* lin_b  = (const float*)d_in[10];

  float* actT = (float*)d_ws;
  float* hbuf = (float*)((char*)d_ws + HBUF_OFF);

  // clear stamps each launch (graph-replay safe: stamps restart at 1)
  hipMemsetAsync(hbuf, 0, HBUF_BYTES, stream);
  hipLaunchKernelGGL(conv_kernel, dim3(B_*16), dim3(512), 192*128*4, stream,
                     inputs, conv_w, conv_b, actT);
  hipLaunchKernelGGL(lstm_kernel, dim3(NG*NCH), dim3(256), 0, stream,
                     actT, w_ih, w_hh, b_ih, b_hh, hbuf);
  hipLaunchKernelGGL(head_kernel, dim3(3), dim3(256), 0, stream,
                     hbuf, lin_w, lin_b, (float*)d_out);
}

// Round 6
// 2414.525 us; speedup vs baseline: 1.7322x; 1.7322x over previous
//
#include <hip/hip_runtime.h>
#include <math.h>

#define B_   64
#define S_   3072
#define DIN  128
#define E_   64
#define H_   256
#define OUT_ 10
#define T_   1024
#define NG   32      // batch groups (2 batches each)
#define GB   2
#define NCH  8       // chunk-WGs per group; WG q owns h-indices [32q,32q+32)
#define GLINES 512   // stamped lines per group per parity: (b, hidx)
#define SLOT 168     // padded k-half slice (168 % 32 = 8 -> bank-disjoint)

// workspace layout (bytes)
#define ACT_BYTES   (B_*E_*T_*4)              // actT[b][e][t] fp32 = 16 MB
#define HBUF_OFF    ACT_BYTES
#define HBUF_BYTES  (NG*2*GLINES*16)          // 512 KB of 16B lines

typedef float f32x4 __attribute__((ext_vector_type(4)));

// IF-coherent access (cross-XCD safe, fence-free). Proven rounds 2/4.
__device__ __forceinline__ f32x4 coh_load_f32x4(const float* p) {
  f32x4 r;
  asm volatile("global_load_dwordx4 %0, %1, off sc0 sc1\n\ts_waitcnt vmcnt(0)"
               : "=v"(r) : "v"(p) : "memory");
  return r;
}
__device__ __forceinline__ void coh_store_f32x4(float* p, f32x4 v) {
  asm volatile("global_store_dwordx4 %0, %1, off sc0 sc1" :: "v"(p), "v"(v) : "memory");
}

__device__ __forceinline__ float fast_sigmoid(float x) {
  return __builtin_amdgcn_rcpf(1.0f + __expf(-x));
}
__device__ __forceinline__ float fast_tanh(float x) {
  return 2.0f * __builtin_amdgcn_rcpf(1.0f + __expf(-2.0f * x)) - 1.0f;
}

// ---------------------------------------------------------------------------
// Conv: normalize rows (L2 over D=128), conv1d k=3 stride=3, +bias, relu.
// ---------------------------------------------------------------------------
__global__ __launch_bounds__(512, 1) void conv_kernel(
    const float* __restrict__ in,     // [B][S][DIN]
    const float* __restrict__ cw,     // [E][DIN][3]
    const float* __restrict__ cb,     // [E]
    float* __restrict__ actT)         // [B][E][T]
{
  extern __shared__ float xs[];                 // 192 rows x 128 f, swizzled
  float4* xs4 = (float4*)xs;
  const int bid = blockIdx.x;
  const int b  = bid >> 4;
  const int tb = bid & 15;
  const int tid = threadIdx.x;

  const float4* gin = (const float4*)(in + (size_t)b*S_*DIN + (size_t)tb*192*DIN);
  #pragma unroll
  for (int i = 0; i < 12; ++i) {
    int f4 = tid + i*512;
    int r = f4 >> 5, dq = f4 & 31;
    xs4[r*32 + (dq ^ (r & 7))] = gin[f4];
  }
  __syncthreads();

  const int wv = tid >> 6, ln = tid & 63;
  for (int rr = 0; rr < 24; ++rr) {
    int r = wv*24 + rr;
    int u = r*32 + ((ln >> 1) ^ (r & 7));
    float2* p = (float2*)((char*)xs + (size_t)u*16 + (size_t)(ln & 1)*8);
    float2 v = *p;
    float s = v.x*v.x + v.y*v.y;
    #pragma unroll
    for (int off = 32; off >= 1; off >>= 1) s += __shfl_xor(s, off);
    float inv = 1.0f / fmaxf(sqrtf(s), 1e-12f);
    v.x *= inv; v.y *= inv;
    *p = v;
  }
  __syncthreads();

  const int eo = __builtin_amdgcn_readfirstlane(wv);
  float acc[8];
  #pragma unroll
  for (int j = 0; j < 8; ++j) acc[j] = cb[eo*8 + j];

  const int r0 = 3*ln, r1 = 3*ln + 1, r2 = 3*ln + 2;
  #pragma unroll 4
  for (int dq = 0; dq < 32; ++dq) {
    float4 x0 = xs4[r0*32 + (dq ^ (r0 & 7))];
    float4 x1 = xs4[r1*32 + (dq ^ (r1 & 7))];
    float4 x2 = xs4[r2*32 + (dq ^ (r2 & 7))];
    #pragma unroll
    for (int j = 0; j < 8; ++j) {
      const float* wp = cw + (size_t)(eo*8 + j)*(DIN*3) + dq*12;  // uniform
      acc[j] += x0.x*wp[0] + x1.x*wp[1] + x2.x*wp[2]
              + x0.y*wp[3] + x1.y*wp[4] + x2.y*wp[5]
              + x0.z*wp[6] + x1.z*wp[7] + x2.z*wp[8]
              + x0.w*wp[9] + x1.w*wp[10] + x2.w*wp[11];
    }
  }

  const int tg = tb*64 + ln;
  #pragma unroll
  for (int j = 0; j < 8; ++j) {
    int e = eo*8 + j;
    actT[(size_t)b*E_*T_ + (size_t)e*T_ + tg] = fmaxf(acc[j], 0.0f);
  }
}

// ---------------------------------------------------------------------------
// LSTM: 256 WGs = 32 groups x 8 chunks; group g = bid&31 (batches 2g,2g+1),
// chunk q = bid>>5 (h-indices [32q,32q+32)). 512 threads = 8 waves.
// Lane role: khalf = l&1 (k-half of row), m = (l>>1)&3 (gate), hh_loc = l>>3.
// Wave role: b = w&1 (batch), hh_half = w>>1. Each thread: half a gate row
// (160 w floats in VGPR). khalf-reduce = shfl_xor(1); gate butterfly =
// shfl_xor(2,4); cell update redundant per octet; lane l&7==0 stores the
// stamped h line. One barrier per step, no LDS scratch, no F-phase.
// h exchange: 16B lines {h, 0, 0, stamp}, one per (b, hidx); each thread
// polls exactly one line (512 lines = 512 threads).
// ---------------------------------------------------------------------------
__global__ __launch_bounds__(512, 1) void lstm_kernel(
    const float* __restrict__ actT,   // [B][E][T]
    const float* __restrict__ w_ih,   // [1024][64]
    const float* __restrict__ w_hh,   // [1024][256]
    const float* __restrict__ b_ih,
    const float* __restrict__ b_hh,
    float* hbuf)                      // [NG][2][GLINES] f32x4 lines
{
  __shared__ float sl[2][2][2][SLOT]; // [parity][b][khalf][slot]

  const int bid = blockIdx.x;
  const int g = bid & 31;
  const int q = bid >> 5;
  const int tid = threadIdx.x;
  const int w = tid >> 6;
  const int l = tid & 63;

  const int khalf = l & 1;
  const int m     = (l >> 1) & 3;
  const int b     = w & 1;
  const int hh    = (w >> 1)*8 + (l >> 3);     // 0..31 within chunk
  const int row   = m*256 + 32*q + hh;         // gate row in [0,1024)

  // weights -> VGPRs: 40 f4 = half-row k in [khalf*160, khalf*160+160)
  // khalf=0: w_hh k 0..159. khalf=1: w_hh k 160..255 (24 f4) + w_ih (16 f4).
  float4 wv[40];
  if (khalf == 0) {
    const float4* ph = (const float4*)(w_hh + (size_t)row*H_);
    #pragma unroll
    for (int i = 0; i < 40; ++i) wv[i] = ph[i];
  } else {
    const float4* ph = (const float4*)(w_hh + (size_t)row*H_) + 40;
    #pragma unroll
    for (int i = 0; i < 24; ++i) wv[i] = ph[i];
    const float4* px = (const float4*)(w_ih + (size_t)row*E_);
    #pragma unroll
    for (int i = 0; i < 16; ++i) wv[24+i] = px[i];
  }
  const float bias = (khalf == 0) ? (b_ih[row] + b_hh[row]) : 0.0f;

  // zero all LDS h/x slices (t=0 uses parity-0 h = 0)
  for (int i = tid; i < 2*2*2*SLOT; i += 512) ((float*)sl)[i] = 0.0f;

  // poll role: line (pb, pidx); LDS target (kh, slot)
  const int pb   = tid >> 8;
  const int pidx = tid & 255;
  const int pkh  = (pidx < 160) ? 0 : 1;
  const int pslot= (pidx < 160) ? pidx : pidx - 160;

  // x role: threads 384..511 load GB*E_=128 x values
  const int xb = ((tid - 384) >> 6) & 1, xe = tid & 63;
  const float* actp = actT + (size_t)((g*GB + xb)*E_ + xe)*T_;
  const bool is_x = (tid >= 384);

  float* hb = hbuf + (size_t)g*(2*GLINES*4);   // floats

  float c = 0.0f;
  for (int t = 0; t < T_; ++t) {
    const int p = t & 1;

    // x prefetch (independent; issued before the poll)
    float xval = 0.0f;
    if (is_x) xval = actp[t];

    // poll my line (frozen at stamp t until this WG passes the barrier)
    if (t > 0) {
      const float* lp = hb + (size_t)(p*GLINES + pb*256 + pidx)*4;
      f32x4 v = coh_load_f32x4(lp);
      while (__float_as_int(v[3]) != t) v = coh_load_f32x4(lp);
      sl[p][pb][pkh][pslot] = v[0];
    }
    if (is_x) sl[p][xb][1][96 + xe] = xval;
    __syncthreads();

    // half-row GEMV: 40 f4 broadcast LDS reads (2 bank-disjoint addrs/instr)
    float acc = bias;
    {
      const float* hs = &sl[p][b][khalf][0];
      #pragma unroll
      for (int i = 0; i < 40; ++i) {
        float4 h4 = *(const float4*)(hs + i*4);
        acc += wv[i].x*h4.x + wv[i].y*h4.y + wv[i].z*h4.z + wv[i].w*h4.w;
      }
    }

    // k-half reduce + gate butterfly (lane bits: khalf=1, m=2|4)
    float ksum = acc + __shfl_xor(acc, 1);
    float x1 = __shfl_xor(ksum, 2);    // gate m^1
    float x2 = __shfl_xor(ksum, 4);    // gate m^2
    float x3 = __shfl_xor(x1, 4);      // gate m^3
    float gi = (m==0)?ksum:(m==1)?x1 :(m==2)?x2 :x3;
    float gf = (m==0)?x1 :(m==1)?ksum:(m==2)?x3 :x2;
    float gg = (m==0)?x2 :(m==1)?x3 :(m==2)?ksum:x1;
    float go = (m==0)?x3 :(m==1)?x2 :(m==2)?x1 :ksum;

    float si = fast_sigmoid(gi);
    float sf = fast_sigmoid(gf);
    float so = fast_sigmoid(go);
    c = sf*c + si*fast_tanh(gg);
    float h = so*fast_tanh(c);

    // store this cell's stamped line (lane khalf==0, m==0 of each octet)
    if ((l & 7) == 0) {
      f32x4 line;
      line[0] = h; line[1] = 0.f; line[2] = 0.f;
      line[3] = __int_as_float(t + 1);
      float* dp = hb + (size_t)((((t+1) & 1)*GLINES) + b*256 + 32*q + hh)*4;
      coh_store_f32x4(dp, line);
    }
  }
}

// ---------------------------------------------------------------------------
// Head: out[b][o] = h_last[b] . lin_w[o] + lin_b[o]
// h_last lives in hbuf parity-0 lines (final store: t+1 = 1024, parity 0).
// ---------------------------------------------------------------------------
__global__ void head_kernel(const float* __restrict__ hbuf,
                            const float* __restrict__ lw,
                            const float* __restrict__ lb,
                            float* __restrict__ out)
{
  int idx = blockIdx.x*blockDim.x + threadIdx.x;
  if (idx >= B_*OUT_) return;
  int b = idx / OUT_, o = idx % OUT_;
  int g = b >> 1, bl = b & 1;
  const float* lines = hbuf + (size_t)g*(2*GLINES*4);   // parity 0 first
  const float* wv = lw + (size_t)o*H_;
  float s = lb[o];
  #pragma unroll 8
  for (int k = 0; k < H_; ++k) s += lines[(size_t)(bl*256 + k)*4] * wv[k];
  out[idx] = s;
}

extern "C" void kernel_launch(void* const* d_in, const int* in_sizes, int n_in,
                              void* d_out, int out_size, void* d_ws, size_t ws_size,
                              hipStream_t stream) {
  const float* inputs = (const float*)d_in[0];
  const float* conv_w = (const float*)d_in[3];
  const float* conv_b = (const float*)d_in[4];
  const float* w_ih   = (const float*)d_in[5];
  const float* w_hh   = (const float*)d_in[6];
  const float* b_ih   = (const float*)d_in[7];
  const float* b_hh   = (const float*)d_in[8];
  const float* lin_w  = (const float*)d_in[9];
  const float* lin_b  = (const float*)d_in[10];

  float* actT = (float*)d_ws;
  float* hbuf = (float*)((char*)d_ws + HBUF_OFF);

  // clear stamps each launch (graph-replay safe: stamps restart at 1)
  hipMemsetAsync(hbuf, 0, HBUF_BYTES, stream);
  hipLaunchKernelGGL(conv_kernel, dim3(B_*16), dim3(512), 192*128*4, stream,
                     inputs, conv_w, conv_b, actT);
  hipLaunchKernelGGL(lstm_kernel, dim3(NG*NCH), dim3(512), 0, stream,
                     actT, w_ih, w_hh, b_ih, b_hh, hbuf);
  hipLaunchKernelGGL(head_kernel, dim3(3), dim3(256), 0, stream,
                     hbuf, lin_w, lin_b, (float*)d_out);
}

// Round 7
// 2118.284 us; speedup vs baseline: 1.9744x; 1.1398x over previous
//
#include <hip/hip_runtime.h>
#include <math.h>

#define B_   64
#define S_   3072
#define DIN  128
#define E_   64
#define H_   256
#define OUT_ 10
#define T_   1024
#define NG   32      // batch groups (2 batches each)
#define GB   2
#define NCH  8       // chunk-WGs per group; WG q owns h-indices [32q,32q+32)
#define NLINES 192   // stamped lines per group per parity: [q][wave][s] 8*8*3
#define SLOT 168     // padded k-half slice (168 % 32 = 8 -> bank-disjoint)

// workspace layout (bytes)
#define ACT_BYTES   (B_*E_*T_*4)              // actT[b][e][t] fp32 = 16 MB
#define HBUF_OFF    ACT_BYTES
#define HBUF_BYTES  (NG*2*NLINES*16)          // 192 KB of 16B lines
#define HFINAL_OFF  (HBUF_OFF + HBUF_BYTES)
#define HFINAL_BYTES (NG*GB*H_*4)             // 128 KB

typedef float f32x4 __attribute__((ext_vector_type(4)));

// IF-coherent access (cross-XCD safe, fence-free). Proven rounds 2/4/6.
__device__ __forceinline__ f32x4 coh_load_f32x4(const float* p) {
  f32x4 r;
  asm volatile("global_load_dwordx4 %0, %1, off sc0 sc1\n\ts_waitcnt vmcnt(0)"
               : "=v"(r) : "v"(p) : "memory");
  return r;
}
__device__ __forceinline__ void coh_store_f32x4(float* p, f32x4 v) {
  asm volatile("global_store_dwordx4 %0, %1, off sc0 sc1" :: "v"(p), "v"(v) : "memory");
}

__device__ __forceinline__ float fast_sigmoid(float x) {
  return __builtin_amdgcn_rcpf(1.0f + __expf(-x));
}
__device__ __forceinline__ float fast_tanh(float x) {
  return 2.0f * __builtin_amdgcn_rcpf(1.0f + __expf(-2.0f * x)) - 1.0f;
}

// ---------------------------------------------------------------------------
// Conv: normalize rows (L2 over D=128), conv1d k=3 stride=3, +bias, relu.
// ---------------------------------------------------------------------------
__global__ __launch_bounds__(512, 1) void conv_kernel(
    const float* __restrict__ in,     // [B][S][DIN]
    const float* __restrict__ cw,     // [E][DIN][3]
    const float* __restrict__ cb,     // [E]
    float* __restrict__ actT)         // [B][E][T]
{
  extern __shared__ float xs[];                 // 192 rows x 128 f, swizzled
  float4* xs4 = (float4*)xs;
  const int bid = blockIdx.x;
  const int b  = bid >> 4;
  const int tb = bid & 15;
  const int tid = threadIdx.x;

  const float4* gin = (const float4*)(in + (size_t)b*S_*DIN + (size_t)tb*192*DIN);
  #pragma unroll
  for (int i = 0; i < 12; ++i) {
    int f4 = tid + i*512;
    int r = f4 >> 5, dq = f4 & 31;
    xs4[r*32 + (dq ^ (r & 7))] = gin[f4];
  }
  __syncthreads();

  const int wv = tid >> 6, ln = tid & 63;
  for (int rr = 0; rr < 24; ++rr) {
    int r = wv*24 + rr;
    int u = r*32 + ((ln >> 1) ^ (r & 7));
    float2* p = (float2*)((char*)xs + (size_t)u*16 + (size_t)(ln & 1)*8);
    float2 v = *p;
    float s = v.x*v.x + v.y*v.y;
    #pragma unroll
    for (int off = 32; off >= 1; off >>= 1) s += __shfl_xor(s, off);
    float inv = 1.0f / fmaxf(sqrtf(s), 1e-12f);
    v.x *= inv; v.y *= inv;
    *p = v;
  }
  __syncthreads();

  const int eo = __builtin_amdgcn_readfirstlane(wv);
  float acc[8];
  #pragma unroll
  for (int j = 0; j < 8; ++j) acc[j] = cb[eo*8 + j];

  const int r0 = 3*ln, r1 = 3*ln + 1, r2 = 3*ln + 2;
  #pragma unroll 4
  for (int dq = 0; dq < 32; ++dq) {
    float4 x0 = xs4[r0*32 + (dq ^ (r0 & 7))];
    float4 x1 = xs4[r1*32 + (dq ^ (r1 & 7))];
    float4 x2 = xs4[r2*32 + (dq ^ (r2 & 7))];
    #pragma unroll
    for (int j = 0; j < 8; ++j) {
      const float* wp = cw + (size_t)(eo*8 + j)*(DIN*3) + dq*12;  // uniform
      acc[j] += x0.x*wp[0] + x1.x*wp[1] + x2.x*wp[2]
              + x0.y*wp[3] + x1.y*wp[4] + x2.y*wp[5]
              + x0.z*wp[6] + x1.z*wp[7] + x2.z*wp[8]
              + x0.w*wp[9] + x1.w*wp[10] + x2.w*wp[11];
    }
  }

  const int tg = tb*64 + ln;
  #pragma unroll
  for (int j = 0; j < 8; ++j) {
    int e = eo*8 + j;
    actT[(size_t)b*E_*T_ + (size_t)e*T_ + tg] = fmaxf(acc[j], 0.0f);
  }
}

// k index -> (khalf, slot) in the 0-conflict LDS layout
__device__ __forceinline__ void kmap(int hidx, int& kh, int& slot) {
  kh = (hidx < 160) ? 0 : 1;
  slot = (hidx < 160) ? hidx : hidx - 160;
}

// ---------------------------------------------------------------------------
// LSTM: 256 WGs = 32 groups x 8 chunks; group g = bid&31 (batches 2g,2g+1),
// chunk q = bid>>5 (h-indices [32q,32q+32)). 512 threads = 8 waves.
// Lane: khalf=l&1, m=(l>>1)&3, octet o=l>>3. Wave: b=w&1, wh=w>>1.
// Thread = half a gate row (160 w floats in VGPR); shfl_xor(1)=k-reduce,
// shfl_xor(2,4)=gate butterfly; cell update redundant per octet.
// h exchange: stamped 16B lines {h0,h1,h2,stamp}, 3 values packed per line
// within each wave -> 24 stores/WG/step; 168 remote lines polled by 168
// threads; own chunk bypasses global entirely (direct LDS write, safe
// because all waves passed barrier t before any thread stores step t).
// ---------------------------------------------------------------------------
__global__ __launch_bounds__(512, 1) void lstm_kernel(
    const float* __restrict__ actT,   // [B][E][T]
    const float* __restrict__ w_ih,   // [1024][64]
    const float* __restrict__ w_hh,   // [1024][256]
    const float* __restrict__ b_ih,
    const float* __restrict__ b_hh,
    float* hbuf,                      // [NG][2][NLINES] f32x4 lines
    float* hfinal)                    // [NG][GB][H]
{
  __shared__ float sl[2][2][2][SLOT]; // [parity][b][khalf][slot]

  const int bid = blockIdx.x;
  const int g = bid & 31;
  const int q = bid >> 5;
  const int tid = threadIdx.x;
  const int w = tid >> 6;
  const int l = tid & 63;

  const int khalf = l & 1;
  const int m     = (l >> 1) & 3;
  const int o     = l >> 3;                    // octet within wave
  const int b     = w & 1;
  const int wh    = w >> 1;
  const int hh    = wh*8 + o;                  // 0..31 within chunk
  const int row   = m*256 + 32*q + hh;         // gate row in [0,1024)

  // weights -> VGPRs: 40 f4 = half-row
  float4 wv[40];
  if (khalf == 0) {
    const float4* ph = (const float4*)(w_hh + (size_t)row*H_);
    #pragma unroll
    for (int i = 0; i < 40; ++i) wv[i] = ph[i];
  } else {
    const float4* ph = (const float4*)(w_hh + (size_t)row*H_) + 40;
    #pragma unroll
    for (int i = 0; i < 24; ++i) wv[i] = ph[i];
    const float4* px = (const float4*)(w_ih + (size_t)row*E_);
    #pragma unroll
    for (int i = 0; i < 16; ++i) wv[24+i] = px[i];
  }
  const float bias = (khalf == 0) ? (b_ih[row] + b_hh[row]) : 0.0f;

  // zero all LDS slices (t=0 parity-0 h = 0)
  for (int i = tid; i < 2*2*2*SLOT; i += 512) ((float*)sl)[i] = 0.0f;

  // poller role: tid<192 maps to line (pq, pw, ps); skip own chunk
  const int pq = tid / 24, pw = (tid % 24) / 3, ps = tid % 3;
  const bool is_poll = (tid < 192) && (pq != q);
  const int pb = pw & 1;
  const int phh0 = 32*pq + (pw >> 1)*8 + 3*ps;  // first h index in line
  const int pcnt = (ps == 2) ? 2 : 3;

  // x loader role: tid in [384,512) loads GB*E_=128 x values
  const bool is_x = (tid >= 384);
  const int xi = tid - 384, xb = (xi >> 6) & 1, xe = xi & 63;
  const float* actp = actT + (size_t)((g*GB + xb)*E_ + xe)*T_;

  // store-lane role: l in {0,24,48} stores line s = l/24 of wave w
  const int ss = l / 24;                       // valid when l%24==0
  const bool is_store = ((l % 24) == 0);
  const int sline = q*24 + w*3 + ss;           // line index within parity
  const int shh0 = wh*8 + 3*ss;                // first local hh in line
  const int scnt = (ss == 2) ? 2 : 3;

  float* hb = hbuf + (size_t)g*(2*NLINES*4);   // floats

  __syncthreads();

  float c = 0.0f;
  for (int t = 0; t < T_; ++t) {
    const int p = t & 1;

    // x prefetch (independent; issued before the poll)
    float xval = 0.0f;
    if (is_x) xval = actp[t];

    // poll my remote line (frozen at stamp t until this WG passes barrier)
    if (t > 0 && is_poll) {
      const float* lp = hb + (size_t)(p*NLINES + tid)*4;
      f32x4 v = coh_load_f32x4(lp);
      while (__float_as_int(v[3]) != t) v = coh_load_f32x4(lp);
      #pragma unroll
      for (int j = 0; j < 3; ++j) {
        if (j < pcnt) {
          int kh, slot; kmap(phh0 + j, kh, slot);
          sl[p][pb][kh][slot] = v[j];
        }
      }
    }
    if (is_x) sl[p][xb][1][96 + xe] = xval;
    __syncthreads();

    // half-row GEMV: 40 f4 broadcast LDS reads (2-way, free)
    float acc = bias;
    {
      const float* hs = &sl[p][b][khalf][0];
      #pragma unroll
      for (int i = 0; i < 40; ++i) {
        float4 h4 = *(const float4*)(hs + i*4);
        acc += wv[i].x*h4.x + wv[i].y*h4.y + wv[i].z*h4.z + wv[i].w*h4.w;
      }
    }

    // k-half reduce + gate butterfly (lane bits: khalf=1, m=2|4)
    float ksum = acc + __shfl_xor(acc, 1);
    float x1 = __shfl_xor(ksum, 2);    // gate m^1
    float x2 = __shfl_xor(ksum, 4);    // gate m^2
    float x3 = __shfl_xor(x1, 4);      // gate m^3
    float gi = (m==0)?ksum:(m==1)?x1 :(m==2)?x2 :x3;
    float gf = (m==0)?x1 :(m==1)?ksum:(m==2)?x3 :x2;
    float gg = (m==0)?x2 :(m==1)?x3 :(m==2)?ksum:x1;
    float go = (m==0)?x3 :(m==1)?x2 :(m==2)?x1 :ksum;

    float si = fast_sigmoid(gi);
    float sf = fast_sigmoid(gf);
    float so = fast_sigmoid(go);
    c = sf*c + si*fast_tanh(gg);
    float h = so*fast_tanh(c);

    // pack 3 octet-values into the store lane (wave-internal shfl)
    float v1 = __shfl(h, (l + 8) & 63, 64);
    float v2 = __shfl(h, (l + 16) & 63, 64);
    if (is_store) {
      f32x4 line;
      line[0] = h; line[1] = v1; line[2] = v2;
      line[3] = __int_as_float(t + 1);
      float* dp = hb + (size_t)((((t+1) & 1)*NLINES) + sline)*4;
      coh_store_f32x4(dp, line);
      // self-chunk bypass: write own h straight into next-parity LDS
      // (safe: every wave passed barrier t, so no reader of sl[p^1] remains;
      //  readers of this data sync on barrier t+1)
      #pragma unroll
      for (int j = 0; j < 3; ++j) {
        if (j < scnt) {
          int kh, slot; kmap(32*q + shh0 + j, kh, slot);
          sl[p ^ 1][b][kh][slot] = (j == 0) ? h : (j == 1) ? v1 : v2;
        }
      }
      if (t == T_ - 1) {
        // plain stores; kernel boundary releases to head_kernel
        #pragma unroll
        for (int j = 0; j < 3; ++j)
          if (j < scnt)
            hfinal[(size_t)g*GB*H_ + (size_t)b*H_ + 32*q + shh0 + j]
                = (j == 0) ? h : (j == 1) ? v1 : v2;
      }
    }
  }
}

// ---------------------------------------------------------------------------
// Head: out[b][o] = h_last[b] . lin_w[o] + lin_b[o]
// ---------------------------------------------------------------------------
__global__ void head_kernel(const float* __restrict__ hfinal,
                            const float* __restrict__ lw,
                            const float* __restrict__ lb,
                            float* __restrict__ out)
{
  int idx = blockIdx.x*blockDim.x + threadIdx.x;
  if (idx >= B_*OUT_) return;
  int b = idx / OUT_, o = idx % OUT_;
  int g = b >> 1, bl = b & 1;
  const float* h = hfinal + (size_t)g*GB*H_ + (size_t)bl*H_;
  const float* wv = lw + (size_t)o*H_;
  float s = lb[o];
  #pragma unroll 8
  for (int k = 0; k < H_; ++k) s += h[k]*wv[k];
  out[idx] = s;
}

extern "C" void kernel_launch(void* const* d_in, const int* in_sizes, int n_in,
                              void* d_out, int out_size, void* d_ws, size_t ws_size,
                              hipStream_t stream) {
  const float* inputs = (const float*)d_in[0];
  const float* conv_w = (const float*)d_in[3];
  const float* conv_b = (const float*)d_in[4];
  const float* w_ih   = (const float*)d_in[5];
  const float* w_hh   = (const float*)d_in[6];
  const float* b_ih   = (const float*)d_in[7];
  const float* b_hh   = (const float*)d_in[8];
  const float* lin_w  = (const float*)d_in[9];
  const float* lin_b  = (const float*)d_in[10];

  float* actT   = (float*)d_ws;
  float* hbuf   = (float*)((char*)d_ws + HBUF_OFF);
  float* hfinal = (float*)((char*)d_ws + HFINAL_OFF);

  // clear stamps each launch (graph-replay safe: stamps restart at 1)
  hipMemsetAsync(hbuf, 0, HBUF_BYTES, stream);
  hipLaunchKernelGGL(conv_kernel, dim3(B_*16), dim3(512), 192*128*4, stream,
                     inputs, conv_w, conv_b, actT);
  hipLaunchKernelGGL(lstm_kernel, dim3(NG*NCH), dim3(512), 0, stream,
                     actT, w_ih, w_hh, b_ih, b_hh, hbuf, hfinal);
  hipLaunchKernelGGL(head_kernel, dim3(3), dim3(256), 0, stream,
                     hfinal, lin_w, lin_b, (float*)d_out);
}